// Round 15
// baseline (46.927 us; speedup 1.0000x reference)
//
#include <hip/hip_runtime.h>
#include <cmath>

// Problem constants (fixed by setup_inputs)
constexpr int B = 16, C = 3, H = 544, W = 960;
constexpr int OH = 136, OW = 240;
constexpr size_t HW = (size_t)H * W;

// Wave-autonomous tiling: each 64-lane wave owns an 8x16 output tile
// (2 adjacent output px per lane). No __syncthreads anywhere.
constexpr int TRW = 17;                 // output tile rows per image (136/8)
constexpr int TCW = 15;                 // output tile cols per image (240/16)
constexpr int NTILES = B * TRW * TCW;   // 4080 waves
constexpr int WPB = 2;                  // waves per block (block = 128 thr)
constexpr int NBLK = NTILES / WPB;      // 2040 blocks
constexpr int CPX = NBLK / 8;           // 255 blocks per XCD (exact)

constexpr int GRr = 38;                 // gray rows: global mh0-3 .. mh0+34
constexpr int GQ = 18;                  // float4 quads per gray row (72 cols)
constexpr int NQ = GRr * GQ;            // 684 = 10*64 + 44
constexpr int GS2 = 76;                 // LDS row stride (floats, +4 pad)
constexpr int NLD = 11;                 // load iterations per lane

__global__ __launch_bounds__(128)
void edge_wave(const float* __restrict__ in, float* __restrict__ out,
               float gn0, float gn1, float gn2)
{
    __shared__ float gray[WPB * GRr * GS2];   // 23104 B

    const int tid  = threadIdx.x;
    const int lane = tid & 63;
    const int wv   = tid >> 6;
    // bijective XCD swizzle: each XCD gets 255 consecutive logical blocks
    const int blk  = ((int)blockIdx.x & 7) * CPX + ((int)blockIdx.x >> 3);
    const int t    = blk * WPB + wv;          // wave-tile id 0..4079
    const int tc   = t % TCW;                 // consecutive tc share L1 halo
    const int tr   = (t / TCW) % TRW;
    const int b    = t / (TCW * TRW);
    const int mh0  = tr * 32, mw0 = tc * 64;
    const float* inb = in + (size_t)b * C * HW;
    float* gw = &gray[wv * GRr * GS2];        // this wave's private region

    // quad q (0..683): row r=q/18 (global mh0-3+r, reflected), colquad cq=q%18
    auto qaddr = [&](int q) -> const float* {
        const int r = q / GQ, cq = q - r * GQ;
        int g = mh0 - 3 + r;                      // row reflect (always valid)
        g = g < 0 ? -g : (g >= H ? 2 * H - 2 - g : g);
        int gcb = mw0 - 4 + 4 * cq;               // col clamp keeps 16B alignment
        gcb = gcb < 0 ? 0 : (gcb > W - 4 ? W - 4 : gcb);
        return inb + (size_t)g * W + gcb;
    };

    // ---- phase A: one 33-VMEM unconditional batch (max in-flight depth) ----
    float4 Rv[NLD], Gv[NLD], Bv[NLD];
    #pragma unroll
    for (int k = 0; k < NLD; ++k) {
        int q = lane + 64 * k;
        q = q < NQ ? q : NQ - 1;                  // tail lanes duplicate
        const float* p = qaddr(q);
        Rv[k] = *reinterpret_cast<const float4*>(p);
        Gv[k] = *reinterpret_cast<const float4*>(p + HW);
        Bv[k] = *reinterpret_cast<const float4*>(p + 2 * HW);
    }
    #pragma unroll
    for (int k = 0; k < NLD; ++k) {
        const int q = lane + 64 * k;
        if (q < NQ) {
            const int r = q / GQ, cq = q - r * GQ;
            float4 g;
            g.x = fmaf(0.2989f, Rv[k].x, fmaf(0.587f, Gv[k].x, 0.114f * Bv[k].x));
            g.y = fmaf(0.2989f, Rv[k].y, fmaf(0.587f, Gv[k].y, 0.114f * Bv[k].y));
            g.z = fmaf(0.2989f, Rv[k].z, fmaf(0.587f, Gv[k].z, 0.114f * Bv[k].z));
            g.w = fmaf(0.2989f, Rv[k].w, fmaf(0.587f, Gv[k].w, 0.114f * Bv[k].w));
            *reinterpret_cast<float4*>(&gw[r * GS2 + 4 * cq]) = g;
        }
    }

    // intra-wave LDS visibility: wave lockstep + lgkmcnt drain (no s_barrier)
    asm volatile("s_waitcnt lgkmcnt(0)" ::: "memory");
    __builtin_amdgcn_sched_barrier(0);

    // ---- column-reflect fixup (only 2/15 tile columns; wave-uniform branch) ----
    if (tc == 0) {
        // local cols 0..3 = global -4..-1  <- reflect of global 4..1 = local 8..5
        if (lane < GRr) {
            float* g_ = &gw[lane * GS2];
            const float4 v = make_float4(g_[8], g_[7], g_[6], g_[5]);
            *reinterpret_cast<float4*>(g_) = v;
        }
    } else if (tc == TCW - 1) {
        // local 68..71 = global 960..963 <- reflect 958..955 = local 66..63
        if (lane < GRr) {
            float* g_ = &gw[lane * GS2];
            const float4 v = make_float4(g_[66], g_[65], g_[64], g_[63]);
            *reinterpret_cast<float4*>(&g_[68]) = v;
        }
    }
    asm volatile("s_waitcnt lgkmcnt(0)" ::: "memory");
    __builtin_amdgcn_sched_barrier(0);

    // ---- phase B: 2 adjacent output px per lane. h-blur rows (16->10),
    //      v-accumulate into sm6[6][10], sobel + pool + sigmoid^2 x2. ----
    __builtin_amdgcn_s_setprio(1);
    {
        const int or_ = lane >> 3;       // output row within tile (0..7)
        const int ocp = lane & 7;        // output col PAIR (cols 2ocp, 2ocp+1)
        const int rb  = 4 * or_;         // gray local row base (reads rb..rb+9)
        const int lc0 = 8 * ocp;         // gray local col base (reads lc0..lc0+15)

        float sm6[6][10];                // smooth rows i=0..5, cols j=0..9
        #pragma unroll
        for (int i = 0; i < 6; ++i)
            #pragma unroll
            for (int j = 0; j < 10; ++j) sm6[i][j] = 0.f;

        const float gk[5] = {gn0, gn1, gn2, gn1, gn0};
        #pragma unroll
        for (int t2 = 0; t2 < 10; ++t2) {
            const float* p = &gw[(rb + t2) * GS2 + lc0];
            const float4 u = *reinterpret_cast<const float4*>(p);
            const float4 v = *reinterpret_cast<const float4*>(p + 4);
            const float4 w = *reinterpret_cast<const float4*>(p + 8);
            const float4 x = *reinterpret_cast<const float4*>(p + 12);
            const float t16[16] = {u.x, u.y, u.z, u.w, v.x, v.y, v.z, v.w,
                                   w.x, w.y, w.z, w.w, x.x, x.y, x.z, x.w};
            float h10[10];
            #pragma unroll
            for (int j = 0; j < 10; ++j)
                h10[j] = fmaf(gn0, t16[1 + j] + t16[5 + j],
                         fmaf(gn1, t16[2 + j] + t16[4 + j], gn2 * t16[3 + j]));
            #pragma unroll
            for (int i = 0; i < 6; ++i) {
                const int m = t2 - i;
                if (m >= 0 && m < 5) {
                    #pragma unroll
                    for (int j = 0; j < 10; ++j)
                        sm6[i][j] = fmaf(gk[m], h10[j], sm6[i][j]);
                }
            }
        }

        // sobel zero-padding: zero smooth outside the image
        #pragma unroll
        for (int i = 0; i < 6; ++i) {
            const int hh = mh0 + 4 * or_ - 1 + i;
            const float rm = (hh >= 0 && hh < H) ? 1.f : 0.f;
            #pragma unroll
            for (int j = 0; j < 10; ++j) {
                const int ww = mw0 + 8 * ocp - 1 + j;
                sm6[i][j] *= rm * ((ww >= 0 && ww < W) ? 1.f : 0.f);
            }
        }

        // two output pixels: px0 uses sm cols 0..5, px1 uses cols 4..9
        float2 o2;
        #pragma unroll
        for (int px = 0; px < 2; ++px) {
            const int jb = 4 * px;
            float acc[4] = {0.f, 0.f, 0.f, 0.f};
            #pragma unroll
            for (int i = 0; i < 4; ++i) {
                #pragma unroll
                for (int j = 0; j < 4; ++j) {
                    const float a00 = sm6[i][jb + j],     a01 = sm6[i][jb + j + 1],     a02 = sm6[i][jb + j + 2];
                    const float a10 = sm6[i + 1][jb + j],                               a12 = sm6[i + 1][jb + j + 2];
                    const float a20 = sm6[i + 2][jb + j], a21 = sm6[i + 2][jb + j + 1], a22 = sm6[i + 2][jb + j + 2];
                    const float gx = (a02 - a00) + 2.f * (a12 - a10) + (a22 - a20);
                    const float gy = (a20 + 2.f * a21 + a22) - (a00 + 2.f * a01 + a02);
                    acc[i] += sqrtf(gx * gx + gy * gy + 1e-6f);
                }
            }
            const float down = ((acc[0] + acc[1]) + (acc[2] + acc[3])) * (1.f / 16.f);
            const float x = 5.0f * (down - 0.2f);
            const float sg = 1.f / (1.f + __expf(-x));
            (px == 0 ? o2.x : o2.y) = sg * sg;
        }
        float* op = out + ((size_t)b * OH + 8 * tr + or_) * OW + 16 * tc + 2 * ocp;
        *reinterpret_cast<float2*>(op) = o2;
    }
    __builtin_amdgcn_s_setprio(0);
}

extern "C" void kernel_launch(void* const* d_in, const int* in_sizes, int n_in,
                              void* d_out, int out_size, void* d_ws, size_t ws_size,
                              hipStream_t stream) {
    const float* in = (const float*)d_in[0];
    float* out = (float*)d_out;

    // Gaussian 1D coefficients (separable: outer(g,g)/(sum g)^2), exact in double.
    const double g0 = std::exp(-4.0 / 4.5);  // x=2
    const double g1 = std::exp(-1.0 / 4.5);  // x=1
    const double g2 = 1.0;                   // x=0
    const double S = 2.0 * (g0 + g1) + g2;
    const float gn0 = (float)(g0 / S);
    const float gn1 = (float)(g1 / S);
    const float gn2 = (float)(g2 / S);

    hipLaunchKernelGGL(edge_wave, dim3(NBLK), dim3(128), 0, stream,
                       in, out, gn0, gn1, gn2);
}

// Round 16
// 31.767 us; speedup vs baseline: 1.4773x; 1.4773x over previous
//
#include <hip/hip_runtime.h>
#include <cmath>

// Problem constants (fixed by setup_inputs)
constexpr int B = 16, C = 3, H = 544, W = 960;
constexpr int OH = 136, OW = 240;
constexpr size_t HW = (size_t)H * W;

// Wave-autonomous tiling: each 64-lane wave owns an 8x8 output tile.
// No __syncthreads anywhere: all LDS traffic is intra-wave.
constexpr int TRW = 17;                 // output tile rows per image (136/8)
constexpr int TCW = 30;                 // output tile cols per image (240/8)
constexpr int NTILES = B * TRW * TCW;   // 8160 waves
constexpr int WPB = 4;                  // waves per block
constexpr int NBLK = NTILES / WPB;      // 2040 blocks
constexpr int CPX = NBLK / 8;           // 255 blocks per XCD (exact)

constexpr int GRr = 38;                 // gray rows: global mh0-3 .. mh0+34
constexpr int GQ = 10;                  // float4 quads per gray row (40 cols)
constexpr int NQ = GRr * GQ;            // 380 quads (384 slots, 4 dup)
constexpr int GS2 = 44;                 // LDS row stride (floats, +4 pad)
constexpr int NLD = 6;                  // load iterations per lane (single batch)

__global__ __launch_bounds__(256)
void edge_wave(const float* __restrict__ in, float* __restrict__ out,
               float gn0, float gn1, float gn2)
{
    __shared__ float gray[WPB * GRr * GS2];   // 26752 B

    const int tid  = threadIdx.x;
    const int lane = tid & 63;
    const int wv   = tid >> 6;
    // bijective XCD swizzle: each XCD gets 255 consecutive logical blocks
    const int blk  = ((int)blockIdx.x & 7) * CPX + ((int)blockIdx.x >> 3);
    const int t    = blk * WPB + wv;          // wave-tile id 0..8159
    const int tc   = t % TCW;
    const int tr   = (t / TCW) % TRW;
    const int b    = t / (TCW * TRW);
    const int mh0  = tr * 32, mw0 = tc * 32;
    const float* inb = in + (size_t)b * C * HW;
    float* gw = &gray[wv * GRr * GS2];        // this wave's private region

    // quad q (0..379): row r=q/10 (global mh0-3+r, reflected), colquad cq=q%10
    auto qaddr = [&](int q) -> const float* {
        const int r = q / GQ, cq = q - r * GQ;
        int g = mh0 - 3 + r;                      // row reflect (always valid)
        g = g < 0 ? -g : (g >= H ? 2 * H - 2 - g : g);
        int gcb = mw0 - 4 + 4 * cq;               // col clamp keeps 16B alignment
        gcb = gcb < 0 ? 0 : (gcb > W - 4 ? W - 4 : gcb);
        return inb + (size_t)g * W + gcb;
    };

    // ---- phase A: ONE unconditional 18-VMEM batch (max in-flight depth) ----
    float4 Rv[NLD], Gv[NLD], Bv[NLD];
    #pragma unroll
    for (int k = 0; k < NLD; ++k) {
        int q = lane + 64 * k;
        q = q < NQ ? q : NQ - 1;                  // tail lanes duplicate
        const float* p = qaddr(q);
        Rv[k] = *reinterpret_cast<const float4*>(p);
        Gv[k] = *reinterpret_cast<const float4*>(p + HW);
        Bv[k] = *reinterpret_cast<const float4*>(p + 2 * HW);
    }
    #pragma unroll
    for (int k = 0; k < NLD; ++k) {
        const int q = lane + 64 * k;
        if (q < NQ) {
            const int r = q / GQ, cq = q - r * GQ;
            float4 g;
            g.x = fmaf(0.2989f, Rv[k].x, fmaf(0.587f, Gv[k].x, 0.114f * Bv[k].x));
            g.y = fmaf(0.2989f, Rv[k].y, fmaf(0.587f, Gv[k].y, 0.114f * Bv[k].y));
            g.z = fmaf(0.2989f, Rv[k].z, fmaf(0.587f, Gv[k].z, 0.114f * Bv[k].z));
            g.w = fmaf(0.2989f, Rv[k].w, fmaf(0.587f, Gv[k].w, 0.114f * Bv[k].w));
            *reinterpret_cast<float4*>(&gw[r * GS2 + 4 * cq]) = g;
        }
    }

    // intra-wave LDS visibility: wave lockstep + lgkmcnt drain (no s_barrier)
    asm volatile("s_waitcnt lgkmcnt(0)" ::: "memory");
    __builtin_amdgcn_sched_barrier(0);

    // ---- column-reflect fixup (only 2/30 tile columns; wave-uniform branch) ----
    if (tc == 0) {
        // local cols 0..3 = global -4..-1  <- reflect of global 4..1 = local 8..5
        if (lane < GRr) {
            float* g_ = &gw[lane * GS2];
            const float4 v = make_float4(g_[8], g_[7], g_[6], g_[5]);
            *reinterpret_cast<float4*>(g_) = v;
        }
    } else if (tc == TCW - 1) {
        // local 36..39 = global 960..963 <- reflect 958..955 = local 34..31
        if (lane < GRr) {
            float* g_ = &gw[lane * GS2];
            const float4 v = make_float4(g_[34], g_[33], g_[32], g_[31]);
            *reinterpret_cast<float4*>(&g_[36]) = v;
        }
    }
    asm volatile("s_waitcnt lgkmcnt(0)" ::: "memory");
    __builtin_amdgcn_sched_barrier(0);

    // ---- phase B: per-lane output px. h-blur rows (12->6), v-accumulate,
    //      sobel + 4x4 pool + sigmoid^2. ----
    __builtin_amdgcn_s_setprio(1);
    {
        const int or_ = lane >> 3;       // output row within tile (0..7)
        const int oc  = lane & 7;        // output col within tile (0..7)
        const int rb  = 4 * or_;         // gray local row base (reads rb..rb+9)
        const int lc0 = 4 * oc;          // gray local col base (reads lc0..lc0+11)

        float sm6[6][6];
        #pragma unroll
        for (int i = 0; i < 6; ++i)
            #pragma unroll
            for (int j = 0; j < 6; ++j) sm6[i][j] = 0.f;

        const float gk[5] = {gn0, gn1, gn2, gn1, gn0};
        #pragma unroll
        for (int t2 = 0; t2 < 10; ++t2) {
            const float* p = &gw[(rb + t2) * GS2 + lc0];
            const float4 u = *reinterpret_cast<const float4*>(p);
            const float4 v = *reinterpret_cast<const float4*>(p + 4);
            const float4 w = *reinterpret_cast<const float4*>(p + 8);
            const float t12[12] = {u.x, u.y, u.z, u.w, v.x, v.y, v.z, v.w,
                                   w.x, w.y, w.z, w.w};
            float h6[6];
            #pragma unroll
            for (int j = 0; j < 6; ++j)
                h6[j] = fmaf(gn0, t12[1 + j] + t12[5 + j],
                        fmaf(gn1, t12[2 + j] + t12[4 + j], gn2 * t12[3 + j]));
            #pragma unroll
            for (int i = 0; i < 6; ++i) {
                const int m = t2 - i;
                if (m >= 0 && m < 5) {
                    #pragma unroll
                    for (int j = 0; j < 6; ++j)
                        sm6[i][j] = fmaf(gk[m], h6[j], sm6[i][j]);
                }
            }
        }

        // sobel zero-padding: zero smooth outside the image
        #pragma unroll
        for (int i = 0; i < 6; ++i) {
            const int hh = mh0 + 4 * or_ - 1 + i;
            const float rm = (hh >= 0 && hh < H) ? 1.f : 0.f;
            #pragma unroll
            for (int j = 0; j < 6; ++j) {
                const int ww = mw0 + 4 * oc - 1 + j;
                sm6[i][j] *= rm * ((ww >= 0 && ww < W) ? 1.f : 0.f);
            }
        }

        // sobel + mag + 4x4 pool (4 independent accumulators) + sigmoid^2
        float acc[4] = {0.f, 0.f, 0.f, 0.f};
        #pragma unroll
        for (int i = 0; i < 4; ++i) {
            #pragma unroll
            for (int j = 0; j < 4; ++j) {
                const float a00 = sm6[i][j],     a01 = sm6[i][j + 1],     a02 = sm6[i][j + 2];
                const float a10 = sm6[i + 1][j],                          a12 = sm6[i + 1][j + 2];
                const float a20 = sm6[i + 2][j], a21 = sm6[i + 2][j + 1], a22 = sm6[i + 2][j + 2];
                const float gx = (a02 - a00) + 2.f * (a12 - a10) + (a22 - a20);
                const float gy = (a20 + 2.f * a21 + a22) - (a00 + 2.f * a01 + a02);
                acc[i] += sqrtf(gx * gx + gy * gy + 1e-6f);
            }
        }
        const float down = ((acc[0] + acc[1]) + (acc[2] + acc[3])) * (1.f / 16.f);
        const float x = 5.0f * (down - 0.2f);
        const float sg = 1.f / (1.f + __expf(-x));
        out[((size_t)b * OH + 8 * tr + or_) * OW + 8 * tc + oc] = sg * sg;
    }
    __builtin_amdgcn_s_setprio(0);
}

extern "C" void kernel_launch(void* const* d_in, const int* in_sizes, int n_in,
                              void* d_out, int out_size, void* d_ws, size_t ws_size,
                              hipStream_t stream) {
    const float* in = (const float*)d_in[0];
    float* out = (float*)d_out;

    // Gaussian 1D coefficients (separable: outer(g,g)/(sum g)^2), exact in double.
    const double g0 = std::exp(-4.0 / 4.5);  // x=2
    const double g1 = std::exp(-1.0 / 4.5);  // x=1
    const double g2 = 1.0;                   // x=0
    const double S = 2.0 * (g0 + g1) + g2;
    const float gn0 = (float)(g0 / S);
    const float gn1 = (float)(g1 / S);
    const float gn2 = (float)(g2 / S);

    hipLaunchKernelGGL(edge_wave, dim3(NBLK), dim3(256), 0, stream,
                       in, out, gn0, gn1, gn2);
}

// Round 17
// 29.332 us; speedup vs baseline: 1.5999x; 1.0830x over previous
//
#include <hip/hip_runtime.h>
#include <cmath>

// Problem constants (fixed by setup_inputs)
constexpr int B = 16, C = 3, H = 544, W = 960;
constexpr int OH = 136, OW = 240;
constexpr size_t HW = (size_t)H * W;

// Wave-autonomous tiling: each 64-lane wave owns an 8x8 output tile.
// No __syncthreads anywhere: all LDS traffic is intra-wave.
constexpr int TRW = 17;                 // output tile rows per image (136/8)
constexpr int TCW = 30;                 // output tile cols per image (240/8)
constexpr int NTILES = B * TRW * TCW;   // 8160 waves
constexpr int WPB = 4;                  // waves per block
constexpr int NBLK = NTILES / WPB;      // 2040 blocks
constexpr int CPX = NBLK / 8;           // 255 blocks per XCD (exact)

constexpr int GRr = 40;                 // gray rows per tile (mh0-4 .. mh0+35)
constexpr int GQ = 10;                  // float4 quads per gray row (40 cols)
constexpr int GS2 = 44;                 // LDS row stride (floats, +4 pad)

__global__ __launch_bounds__(256)
void edge_wave(const float* __restrict__ in, float* __restrict__ out,
               float gn0, float gn1, float gn2)
{
    __shared__ float gray[WPB * GRr * GS2];   // 28160 B

    const int tid  = threadIdx.x;
    const int lane = tid & 63;
    const int wv   = tid >> 6;
    // bijective XCD swizzle: each XCD gets 255 consecutive logical blocks
    const int blk  = ((int)blockIdx.x & 7) * CPX + ((int)blockIdx.x >> 3);
    const int t    = blk * WPB + wv;          // wave-tile id 0..8159
    const int tc   = t % TCW;
    const int tr   = (t / TCW) % TRW;
    const int b    = t / (TCW * TRW);
    const int mh0  = tr * 32, mw0 = tc * 32;
    const float* inb = in + (size_t)b * C * HW;
    float* gw = &gray[wv * GRr * GS2];        // this wave's private region

    // ---- load 400 RGB quads (40 rows x 10 quads): 6 full iters + 16-lane tail.
    //      Loads batched up-front for deep MLP; cols clamped (edges fixed later).
    float4 Rv[7], Gv[7], Bv[7];
    #pragma unroll
    for (int k = 0; k < 6; ++k) {
        const int q = lane + 64 * k;
        const int r = q / GQ, cq = q - r * GQ;
        int g = mh0 - 4 + r;                      // row reflect (always valid)
        g = g < 0 ? -g : (g >= H ? 2 * H - 2 - g : g);
        int gcb = mw0 - 4 + 4 * cq;               // col clamp keeps 16B alignment
        gcb = gcb < 0 ? 0 : (gcb > W - 4 ? W - 4 : gcb);
        const float* p = inb + (size_t)g * W + gcb;
        Rv[k] = *reinterpret_cast<const float4*>(p);
        Gv[k] = *reinterpret_cast<const float4*>(p + HW);
        Bv[k] = *reinterpret_cast<const float4*>(p + 2 * HW);
    }
    if (lane < 16) {
        const int q = lane + 384;
        const int r = q / GQ, cq = q - r * GQ;
        int g = mh0 - 4 + r;
        g = g < 0 ? -g : (g >= H ? 2 * H - 2 - g : g);
        int gcb = mw0 - 4 + 4 * cq;
        gcb = gcb < 0 ? 0 : (gcb > W - 4 ? W - 4 : gcb);
        const float* p = inb + (size_t)g * W + gcb;
        Rv[6] = *reinterpret_cast<const float4*>(p);
        Gv[6] = *reinterpret_cast<const float4*>(p + HW);
        Bv[6] = *reinterpret_cast<const float4*>(p + 2 * HW);
    }

    // ---- convert to gray, write own-wave LDS region ----
    #pragma unroll
    for (int k = 0; k < 6; ++k) {
        const int q = lane + 64 * k;
        const int r = q / GQ, cq = q - r * GQ;
        float4 g;
        g.x = fmaf(0.2989f, Rv[k].x, fmaf(0.587f, Gv[k].x, 0.114f * Bv[k].x));
        g.y = fmaf(0.2989f, Rv[k].y, fmaf(0.587f, Gv[k].y, 0.114f * Bv[k].y));
        g.z = fmaf(0.2989f, Rv[k].z, fmaf(0.587f, Gv[k].z, 0.114f * Bv[k].z));
        g.w = fmaf(0.2989f, Rv[k].w, fmaf(0.587f, Gv[k].w, 0.114f * Bv[k].w));
        *reinterpret_cast<float4*>(&gw[r * GS2 + 4 * cq]) = g;
    }
    if (lane < 16) {
        const int q = lane + 384;
        const int r = q / GQ, cq = q - r * GQ;
        float4 g;
        g.x = fmaf(0.2989f, Rv[6].x, fmaf(0.587f, Gv[6].x, 0.114f * Bv[6].x));
        g.y = fmaf(0.2989f, Rv[6].y, fmaf(0.587f, Gv[6].y, 0.114f * Bv[6].y));
        g.z = fmaf(0.2989f, Rv[6].z, fmaf(0.587f, Gv[6].z, 0.114f * Bv[6].z));
        g.w = fmaf(0.2989f, Rv[6].w, fmaf(0.587f, Gv[6].w, 0.114f * Bv[6].w));
        *reinterpret_cast<float4*>(&gw[r * GS2 + 4 * cq]) = g;
    }

    // intra-wave LDS visibility: wave lockstep + lgkmcnt drain (no s_barrier)
    asm volatile("s_waitcnt lgkmcnt(0)" ::: "memory");
    __builtin_amdgcn_sched_barrier(0);

    // ---- column-reflect fixup (only 2/30 tile columns; wave-uniform branch) ----
    if (tc == 0) {
        // local cols 0..3 = global -4..-1  <- reflect of global 4..1 = local 8..5
        if (lane < GRr) {
            float* g_ = &gw[lane * GS2];
            const float4 v = make_float4(g_[8], g_[7], g_[6], g_[5]);
            *reinterpret_cast<float4*>(g_) = v;
        }
    } else if (tc == TCW - 1) {
        // local 36..39 = global 960..963 <- reflect 958..955 = local 34..31
        if (lane < GRr) {
            float* g_ = &gw[lane * GS2];
            const float4 v = make_float4(g_[34], g_[33], g_[32], g_[31]);
            *reinterpret_cast<float4*>(&g_[36]) = v;
        }
    }
    asm volatile("s_waitcnt lgkmcnt(0)" ::: "memory");
    __builtin_amdgcn_sched_barrier(0);

    // ---- phase B: per-lane output px. h-blur rows (12->6), v-accumulate,
    //      sobel + 4x4 pool + sigmoid^2. ----
    __builtin_amdgcn_s_setprio(1);
    {
        const int or_ = lane >> 3;       // output row within tile (0..7)
        const int oc  = lane & 7;        // output col within tile (0..7)
        const int rb  = 4 * or_ + 1;     // gray local row base (reads rb..rb+9)
        const int lc0 = 4 * oc;          // gray local col base (reads lc0..lc0+11)

        float sm6[6][6];
        #pragma unroll
        for (int i = 0; i < 6; ++i)
            #pragma unroll
            for (int j = 0; j < 6; ++j) sm6[i][j] = 0.f;

        const float gk[5] = {gn0, gn1, gn2, gn1, gn0};
        #pragma unroll
        for (int t2 = 0; t2 < 10; ++t2) {
            const float* p = &gw[(rb + t2) * GS2 + lc0];
            const float4 u = *reinterpret_cast<const float4*>(p);
            const float4 v = *reinterpret_cast<const float4*>(p + 4);
            const float4 w = *reinterpret_cast<const float4*>(p + 8);
            const float t12[12] = {u.x, u.y, u.z, u.w, v.x, v.y, v.z, v.w,
                                   w.x, w.y, w.z, w.w};
            float h6[6];
            #pragma unroll
            for (int j = 0; j < 6; ++j)
                h6[j] = fmaf(gn0, t12[1 + j] + t12[5 + j],
                        fmaf(gn1, t12[2 + j] + t12[4 + j], gn2 * t12[3 + j]));
            #pragma unroll
            for (int i = 0; i < 6; ++i) {
                const int m = t2 - i;
                if (m >= 0 && m < 5) {
                    #pragma unroll
                    for (int j = 0; j < 6; ++j)
                        sm6[i][j] = fmaf(gk[m], h6[j], sm6[i][j]);
                }
            }
        }

        // sobel zero-padding: zero smooth outside the image
        #pragma unroll
        for (int i = 0; i < 6; ++i) {
            const int hh = mh0 + 4 * or_ - 1 + i;
            const float rm = (hh >= 0 && hh < H) ? 1.f : 0.f;
            #pragma unroll
            for (int j = 0; j < 6; ++j) {
                const int ww = mw0 + 4 * oc - 1 + j;
                sm6[i][j] *= rm * ((ww >= 0 && ww < W) ? 1.f : 0.f);
            }
        }

        // sobel + mag + 4x4 pool (4 independent accumulators) + sigmoid^2
        float acc[4] = {0.f, 0.f, 0.f, 0.f};
        #pragma unroll
        for (int i = 0; i < 4; ++i) {
            #pragma unroll
            for (int j = 0; j < 4; ++j) {
                const float a00 = sm6[i][j],     a01 = sm6[i][j + 1],     a02 = sm6[i][j + 2];
                const float a10 = sm6[i + 1][j],                          a12 = sm6[i + 1][j + 2];
                const float a20 = sm6[i + 2][j], a21 = sm6[i + 2][j + 1], a22 = sm6[i + 2][j + 2];
                const float gx = (a02 - a00) + 2.f * (a12 - a10) + (a22 - a20);
                const float gy = (a20 + 2.f * a21 + a22) - (a00 + 2.f * a01 + a02);
                acc[i] += sqrtf(gx * gx + gy * gy + 1e-6f);
            }
        }
        const float down = ((acc[0] + acc[1]) + (acc[2] + acc[3])) * (1.f / 16.f);
        const float x = 5.0f * (down - 0.2f);
        const float sg = 1.f / (1.f + __expf(-x));
        out[((size_t)b * OH + 8 * tr + or_) * OW + 8 * tc + oc] = sg * sg;
    }
    __builtin_amdgcn_s_setprio(0);
}

extern "C" void kernel_launch(void* const* d_in, const int* in_sizes, int n_in,
                              void* d_out, int out_size, void* d_ws, size_t ws_size,
                              hipStream_t stream) {
    const float* in = (const float*)d_in[0];
    float* out = (float*)d_out;

    // Gaussian 1D coefficients (separable: outer(g,g)/(sum g)^2), exact in double.
    const double g0 = std::exp(-4.0 / 4.5);  // x=2
    const double g1 = std::exp(-1.0 / 4.5);  // x=1
    const double g2 = 1.0;                   // x=0
    const double S = 2.0 * (g0 + g1) + g2;
    const float gn0 = (float)(g0 / S);
    const float gn1 = (float)(g1 / S);
    const float gn2 = (float)(g2 / S);

    hipLaunchKernelGGL(edge_wave, dim3(NBLK), dim3(256), 0, stream,
                       in, out, gn0, gn1, gn2);
}